// Round 11
// baseline (54.079 us; speedup 1.0000x reference)
//
#include <hip/hip_runtime.h>

// PQC: h = tanh(x @ W^T) * scale; 8-qubit circuit via exact transfer-matrix
// contraction (CNOT staircase => MPS bond dim 2; symmetry-reduced 2x3 state).
// R11 = split-K: each wave does 16 samples x half-K (384 cols); block = 4
// waves = 2 groups x 2 K-halves = 32 samples; grid 2048 blocks => 2x waves
// vs R10 (which was grid-limited at 4 waves/SIMD). Halves combined in LDS;
// circuit = verified D-insertion chain, one (sample,wire) per thread (all
// 256 threads), coalesced 1KB store.  W staged in LDS (R10's proven win).

__device__ __forceinline__ float fast_tanh(float v) {
    float e = __expf(2.0f * v);
    return 1.0f - 2.0f / (e + 1.0f);   // exact at +/-inf overflow
}

// one chain site: data/layer0-RY conjugation M(A,B,1-A), then layer1-RY+CNOT mix
__device__ __forceinline__ void fwd_step(float (&L)[2][3], float A, float B,
                                         float c2, float cs) {
    float u[2][3];
    #pragma unroll
    for (int b = 0; b < 2; ++b) {
        const float v0 = L[b][0], v1 = L[b][1], v2 = L[b][2];
        const float d  = v0 - v2;
        const float B2 = B + B;
        u[b][0] = fmaf(A, d, fmaf(B2, v1, v2));      // A v0 + 2B v1 + (1-A) v2
        u[b][1] = fmaf(B, v0 + v2, v1);              // B v0 + v1 + B v2
        u[b][2] = fmaf(-A, d, fmaf(B2, v1, v0));     // (1-A) v0 + 2B v1 + A v2
    }
    const float d0 = u[0][0] - u[1][0];
    L[0][0] = fmaf(c2, d0, u[1][0]);
    L[1][0] = fmaf(-c2, d0, u[0][0]);
    const float m = cs * (u[1][1] - u[0][1]);
    L[0][1] = m;  L[1][1] = -m;
    const float d2 = u[1][2] - u[0][2];
    L[0][2] = fmaf(c2, d2, u[0][2]);
    L[1][2] = fmaf(-c2, d2, u[1][2]);
}

__global__ __launch_bounds__(256)
__attribute__((amdgpu_waves_per_eu(5)))
void pqc_kernel(const float* __restrict__ x,
                const float* __restrict__ Wp,
                const float* __restrict__ scalep,
                const float* __restrict__ wts,
                float* __restrict__ out)
{
    __shared__ float Wl[6144];          // 8 x 768 W tile, 24 KB
    __shared__ float hb[2][2][16][8];   // [group][khalf][row][q] partial h

    const int tid  = threadIdx.x;
    const int lane = tid & 63;
    const int wave = tid >> 6;            // 0..3
    const int g    = wave >> 1;           // sample group 0..1
    const int kh   = wave & 1;            // K-half 0..1
    const int b0   = blockIdx.x * 32;     // 32 samples per block
    const int rbase = b0 + g * 16;

    const int s4  = lane >> 4;            // 0..3  sample sub-group
    const int c16 = lane & 15;            // 0..15 column group

    // ---- stage W into LDS (256 threads x 6 float4) ----
    {
        const float4* Wv4 = reinterpret_cast<const float4*>(Wp);
        float4*       Lv4 = reinterpret_cast<float4*>(Wl);
        #pragma unroll
        for (int k = 0; k < 6; ++k)
            Lv4[tid + k * 256] = Wv4[tid + k * 256];
    }
    __syncthreads();

    // ---------------- projection: 16 samples x 384 cols per wave ----------------
    float acc[4][8];
    #pragma unroll
    for (int p = 0; p < 4; ++p)
        #pragma unroll
        for (int q = 0; q < 8; ++q) acc[p][q] = 0.0f;

    const int colbase = kh * 96 + c16;    // float4 index of this lane's first col

    #pragma unroll 2
    for (int j = 0; j < 6; ++j) {
        const int col4 = colbase + j * 16;
        float4 wv[8];
        #pragma unroll
        for (int q = 0; q < 8; ++q)
            wv[q] = *reinterpret_cast<const float4*>(Wl + q * 768 + col4 * 4);
        #pragma unroll
        for (int p = 0; p < 4; ++p) {
            const float4 xv = *reinterpret_cast<const float4*>(
                x + (size_t)(rbase + p * 4 + s4) * 768 + col4 * 4);
            #pragma unroll
            for (int q = 0; q < 8; ++q) {
                acc[p][q] = fmaf(xv.x, wv[q].x, acc[p][q]);
                acc[p][q] = fmaf(xv.y, wv[q].y, acc[p][q]);
                acc[p][q] = fmaf(xv.z, wv[q].z, acc[p][q]);
                acc[p][q] = fmaf(xv.w, wv[q].w, acc[p][q]);
            }
        }
    }

    // butterfly reduce over the 16 column lanes (bits 0..3)
    #pragma unroll
    for (int m = 1; m <= 8; m <<= 1)
        #pragma unroll
        for (int p = 0; p < 4; ++p)
            #pragma unroll
            for (int q = 0; q < 8; ++q)
                acc[p][q] += __shfl_xor(acc[p][q], m, 64);

    // write this wave's K-half partials
    if (c16 == 0) {
        #pragma unroll
        for (int p = 0; p < 4; ++p)
            #pragma unroll
            for (int q = 0; q < 8; ++q)
                hb[g][kh][p * 4 + s4][q] = acc[p][q];
    }
    __syncthreads();

    // ---------------- circuit: one (sample, wire) per thread ----------------
    const int s5 = tid >> 3;              // 0..31 sample within block
    const int k  = tid & 7;               // wire index
    const float scl = scalep[0];

    float Aq[8], Bq[8], c2q[8], csq[8];
    #pragma unroll
    for (int q = 0; q < 8; ++q) {
        const float hq = hb[s5 >> 4][0][s5 & 15][q] + hb[s5 >> 4][1][s5 & 15][q];
        float ang = fast_tanh(hq) * scl + wts[q];   // fold layer-0 weight RY
        float s, c;
        __sincosf(0.5f * ang, &s, &c);
        Aq[q] = c * c;  Bq[q] = c * s;
        float sw, cw;
        __sincosf(0.5f * wts[8 + q], &sw, &cw);
        c2q[q] = cw * cw;  csq[q] = cw * sw;
    }

    // chain with D-insertion after site k:
    //   z_k = ones^T . M7...M_{k+1} . D . M_k...M0 . e0   (D: negate b=1 block)
    float L[2][3] = {{1.f, 0.f, 0.f}, {0.f, 0.f, 0.f}};
    #pragma unroll
    for (int q = 0; q < 8; ++q) {
        fwd_step(L, Aq[q], Bq[q], c2q[q], csq[q]);
        const float sgn = (q == k) ? -1.f : 1.f;
        L[1][0] *= sgn;  L[1][1] *= sgn;  L[1][2] *= sgn;
    }
    const float zv = (L[0][0] + 2.f * L[0][1] + L[0][2])
                   + (L[1][0] + 2.f * L[1][1] + L[1][2]);

    // coalesced: out[(b0 + s5)*8 + k] = out[b0*8 + tid]
    out[(size_t)b0 * 8 + tid] = zv;
}

extern "C" void kernel_launch(void* const* d_in, const int* in_sizes, int n_in,
                              void* d_out, int out_size, void* d_ws, size_t ws_size,
                              hipStream_t stream) {
    const float* x   = (const float*)d_in[0];
    const float* W   = (const float*)d_in[1];
    const float* sc  = (const float*)d_in[2];
    const float* wt  = (const float*)d_in[3];
    float* o         = (float*)d_out;

    const int batch  = in_sizes[0] / 768;     // 65536
    const int blocks = batch / 32;            // 32 samples per block
    pqc_kernel<<<dim3(blocks), dim3(256), 0, stream>>>(x, W, sc, wt, o);
}

// Round 12
// 45.918 us; speedup vs baseline: 1.1777x; 1.1777x over previous
//
#include <hip/hip_runtime.h>

// PQC: h = tanh(x @ W^T) * scale; 8-qubit circuit via exact transfer-matrix
// contraction (CNOT staircase = prefix-XOR => MPS bond dim 2 per staircase;
// <Z_i> = 1D chain contraction with 2x2x2 state, symmetry-reduced to 2x3).
// R12 = R10 (39.3us: R7 GEMM shape + LDS-W) with ONE change: j-loop unroll
// 2 -> 4 (double the x-loads in flight per wave; we are grid-limited at
// 4 waves/SIMD so MLP must come from ILP). launch_bounds(256,4) caps VGPR
// at 128: no spill, residency stays 4/SIMD.

__device__ __forceinline__ float fast_tanh(float v) {
    float e = __expf(2.0f * v);
    return 1.0f - 2.0f / (e + 1.0f);   // exact at +/-inf overflow
}

__global__ __launch_bounds__(256, 4)
void pqc_kernel(const float* __restrict__ x,
                const float* __restrict__ Wp,
                const float* __restrict__ scalep,
                const float* __restrict__ wts,
                float* __restrict__ out)
{
    __shared__ float hb[64][8];   // per-block projection results (pre-tanh)
    __shared__ float Wl[6144];    // 8 x 768 W tile, 24 KB

    const int tid  = threadIdx.x;
    const int lane = tid & 63;
    const int wave = tid >> 6;            // 0..3
    const int b0   = blockIdx.x * 64;

    const int s4  = lane >> 4;            // 0..3  sample sub-group
    const int c16 = lane & 15;            // 0..15 column group

    // ---- stage W into LDS (256 threads x 6 float4) ----
    {
        const float4* Wv4 = reinterpret_cast<const float4*>(Wp);
        float4*       Lv4 = reinterpret_cast<float4*>(Wl);
        #pragma unroll
        for (int k = 0; k < 6; ++k)
            Lv4[tid + k * 256] = Wv4[tid + k * 256];
    }
    __syncthreads();

    // ---------------- projection phase: this wave's 16 samples ----------------
    const int rbase = b0 + wave * 16;
    float acc[4][8];
    #pragma unroll
    for (int p = 0; p < 4; ++p)
        #pragma unroll
        for (int q = 0; q < 8; ++q) acc[p][q] = 0.0f;

    #pragma unroll 4
    for (int j = 0; j < 12; ++j) {
        const int col4 = j * 16 + c16;    // float4 index within a 768-float row
        float4 wv[8];
        #pragma unroll
        for (int q = 0; q < 8; ++q)
            wv[q] = *reinterpret_cast<const float4*>(Wl + q * 768 + col4 * 4);
        #pragma unroll
        for (int p = 0; p < 4; ++p) {
            const float4 xv = *reinterpret_cast<const float4*>(
                x + (size_t)(rbase + p * 4 + s4) * 768 + col4 * 4);
            #pragma unroll
            for (int q = 0; q < 8; ++q) {
                acc[p][q] = fmaf(xv.x, wv[q].x, acc[p][q]);
                acc[p][q] = fmaf(xv.y, wv[q].y, acc[p][q]);
                acc[p][q] = fmaf(xv.z, wv[q].z, acc[p][q]);
                acc[p][q] = fmaf(xv.w, wv[q].w, acc[p][q]);
            }
        }
    }
    // reduce over the 16 column lanes
    #pragma unroll
    for (int m = 1; m <= 8; m <<= 1)
        #pragma unroll
        for (int p = 0; p < 4; ++p)
            #pragma unroll
            for (int q = 0; q < 8; ++q)
                acc[p][q] += __shfl_xor(acc[p][q], m, 64);

    if (c16 == 0) {
        #pragma unroll
        for (int p = 0; p < 4; ++p) {
            const int srow = wave * 16 + p * 4 + s4;
            #pragma unroll
            for (int q = 0; q < 8; ++q) hb[srow][q] = acc[p][q];
        }
    }
    __syncthreads();

    // ---------------- circuit phase: transfer-matrix, one sample per thread ----
    // Active: lanes 0..15 of each wave -> 64 samples per block, one per thread.
    if (lane < 16) {
        const int sl   = wave * 16 + lane;     // local sample 0..63
        const int samp = b0 + sl;
        const float scl = scalep[0];

        // per-sample single-qubit input amplitudes: f0=cos(phi/2), f1=sin(phi/2)
        // phi folds the data RY and the layer-0 weight RY (both pre-entangler).
        float f0[8], f1[8];
        #pragma unroll
        for (int q = 0; q < 8; ++q) {
            float ang = fast_tanh(hb[sl][q]) * scl + wts[q];
            __sincosf(0.5f * ang, &f1[q], &f0[q]);
        }
        // layer-1 RY params (uniform): G-tables c^2, s^2, c*s
        float c2[8], s2[8], cs[8];
        #pragma unroll
        for (int q = 0; q < 8; ++q) {
            float sw, cw;
            __sincosf(0.5f * wts[8 + q], &sw, &cw);
            c2[q] = cw * cw; s2[q] = sw * sw; cs[q] = cw * sw;
        }

        // state vector over (b, sym(beta,beta~)): [2][3], t: 0=(00),1=(01/10),2=(11)
        // prefix sweep: Lp[q] = L^(q); Lp[0] = e_{b=0,t=0}
        float Lp[9][2][3];
        Lp[0][0][0] = 1.f; Lp[0][0][1] = 0.f; Lp[0][0][2] = 0.f;
        Lp[0][1][0] = 0.f; Lp[0][1][1] = 0.f; Lp[0][1][2] = 0.f;

        #pragma unroll
        for (int q = 0; q < 8; ++q) {
            const float A = f0[q] * f0[q];
            const float B = f0[q] * f1[q];
            const float C = f1[q] * f1[q];
            float u[2][3];
            #pragma unroll
            for (int b = 0; b < 2; ++b) {
                const float v0 = Lp[q][b][0], v1 = Lp[q][b][1], v2 = Lp[q][b][2];
                u[b][0] = A * v0 + 2.f * B * v1 + C * v2;
                u[b][1] = B * v0 + (A + C) * v1 + B * v2;
                u[b][2] = C * v0 + 2.f * B * v1 + A * v2;
            }
            Lp[q+1][0][0] = c2[q] * u[0][0] + s2[q] * u[1][0];
            Lp[q+1][1][0] = s2[q] * u[0][0] + c2[q] * u[1][0];
            const float m = cs[q] * (u[1][1] - u[0][1]);
            Lp[q+1][0][1] = m;
            Lp[q+1][1][1] = -m;
            Lp[q+1][0][2] = s2[q] * u[0][2] + c2[q] * u[1][2];
            Lp[q+1][1][2] = c2[q] * u[0][2] + s2[q] * u[1][2];
        }

        // suffix sweep + signed dots: z_i = <S^(i+1), (+/- on b) L^(i+1)>
        float S[2][3] = {{1.f, 1.f, 1.f}, {1.f, 1.f, 1.f}};
        float z[8];
        #pragma unroll
        for (int i = 7; i >= 0; --i) {
            z[i] = (S[0][0] * Lp[i+1][0][0] + 2.f * S[0][1] * Lp[i+1][0][1] + S[0][2] * Lp[i+1][0][2])
                 - (S[1][0] * Lp[i+1][1][0] + 2.f * S[1][1] * Lp[i+1][1][1] + S[1][2] * Lp[i+1][1][2]);
            if (i > 0) {
                float u[2][3];
                u[0][0] = c2[i] * S[0][0] + s2[i] * S[1][0];
                u[1][0] = s2[i] * S[0][0] + c2[i] * S[1][0];
                const float m = cs[i] * (S[1][1] - S[0][1]);
                u[0][1] = m; u[1][1] = -m;
                u[0][2] = s2[i] * S[0][2] + c2[i] * S[1][2];
                u[1][2] = c2[i] * S[0][2] + s2[i] * S[1][2];
                const float A = f0[i] * f0[i];
                const float B = f0[i] * f1[i];
                const float C = f1[i] * f1[i];
                #pragma unroll
                for (int b = 0; b < 2; ++b) {
                    const float u0 = u[b][0], u1 = u[b][1], u2 = u[b][2];
                    S[b][0] = A * u0 + 2.f * B * u1 + C * u2;
                    S[b][1] = B * u0 + (A + C) * u1 + B * u2;
                    S[b][2] = C * u0 + 2.f * B * u1 + A * u2;
                }
            }
        }

        float4* o = reinterpret_cast<float4*>(out + (size_t)samp * 8);
        o[0] = make_float4(z[0], z[1], z[2], z[3]);
        o[1] = make_float4(z[4], z[5], z[6], z[7]);
    }
}

extern "C" void kernel_launch(void* const* d_in, const int* in_sizes, int n_in,
                              void* d_out, int out_size, void* d_ws, size_t ws_size,
                              hipStream_t stream) {
    const float* x   = (const float*)d_in[0];
    const float* W   = (const float*)d_in[1];
    const float* sc  = (const float*)d_in[2];
    const float* wt  = (const float*)d_in[3];
    float* o         = (float*)d_out;

    const int batch  = in_sizes[0] / 768;     // 65536
    const int blocks = batch / 64;            // 64 samples per block
    pqc_kernel<<<dim3(blocks), dim3(256), 0, stream>>>(x, W, sc, wt, o);
}

// Round 13
// 38.067 us; speedup vs baseline: 1.4206x; 1.2062x over previous
//
#include <hip/hip_runtime.h>

// PQC: h = tanh(x @ W^T) * scale; 8-qubit circuit via exact transfer-matrix
// contraction (CNOT staircase = prefix-XOR => MPS bond dim 2 per staircase;
// <Z_i> = 1D chain contraction with 2x2x2 state, symmetry-reduced to 2x3).
// R13 = R10 (39.3us) with ONE change: the 16-lane butterfly reduce now uses
// VALU-pipe DPP row_ror rotate-and-add (v_add_f32_dpp) instead of
// __shfl_xor (ds_swizzle = LDS pipe). c16 = low 4 lane bits = one DPP row
// half, so row_ror:1/2/4/8 gives every lane the 16-lane sum.

__device__ __forceinline__ float fast_tanh(float v) {
    float e = __expf(2.0f * v);
    return 1.0f - 2.0f / (e + 1.0f);   // exact at +/-inf overflow
}

template<int CTRL>
__device__ __forceinline__ float dpp_rotadd(float v) {
    int s = __builtin_bit_cast(int, v);
    int r = __builtin_amdgcn_update_dpp(s, s, CTRL, 0xf, 0xf, false);
    return v + __builtin_bit_cast(float, r);
}

__device__ __forceinline__ float row16_sum(float v) {
    v = dpp_rotadd<0x121>(v);   // row_ror:1
    v = dpp_rotadd<0x122>(v);   // row_ror:2
    v = dpp_rotadd<0x124>(v);   // row_ror:4
    v = dpp_rotadd<0x128>(v);   // row_ror:8
    return v;
}

__global__ __launch_bounds__(256, 3)
void pqc_kernel(const float* __restrict__ x,
                const float* __restrict__ Wp,
                const float* __restrict__ scalep,
                const float* __restrict__ wts,
                float* __restrict__ out)
{
    __shared__ float hb[64][8];   // per-block projection results (pre-tanh)
    __shared__ float Wl[6144];    // 8 x 768 W tile, 24 KB

    const int tid  = threadIdx.x;
    const int lane = tid & 63;
    const int wave = tid >> 6;            // 0..3
    const int b0   = blockIdx.x * 64;

    const int s4  = lane >> 4;            // 0..3  sample sub-group
    const int c16 = lane & 15;            // 0..15 column group

    // ---- stage W into LDS (256 threads x 6 float4) ----
    {
        const float4* Wv4 = reinterpret_cast<const float4*>(Wp);
        float4*       Lv4 = reinterpret_cast<float4*>(Wl);
        #pragma unroll
        for (int k = 0; k < 6; ++k)
            Lv4[tid + k * 256] = Wv4[tid + k * 256];
    }
    __syncthreads();

    // ---------------- projection phase: this wave's 16 samples ----------------
    const int rbase = b0 + wave * 16;
    float acc[4][8];
    #pragma unroll
    for (int p = 0; p < 4; ++p)
        #pragma unroll
        for (int q = 0; q < 8; ++q) acc[p][q] = 0.0f;

    #pragma unroll 2
    for (int j = 0; j < 12; ++j) {
        const int col4 = j * 16 + c16;    // float4 index within a 768-float row
        float4 wv[8];
        #pragma unroll
        for (int q = 0; q < 8; ++q)
            wv[q] = *reinterpret_cast<const float4*>(Wl + q * 768 + col4 * 4);
        #pragma unroll
        for (int p = 0; p < 4; ++p) {
            const float4 xv = *reinterpret_cast<const float4*>(
                x + (size_t)(rbase + p * 4 + s4) * 768 + col4 * 4);
            #pragma unroll
            for (int q = 0; q < 8; ++q) {
                acc[p][q] = fmaf(xv.x, wv[q].x, acc[p][q]);
                acc[p][q] = fmaf(xv.y, wv[q].y, acc[p][q]);
                acc[p][q] = fmaf(xv.z, wv[q].z, acc[p][q]);
                acc[p][q] = fmaf(xv.w, wv[q].w, acc[p][q]);
            }
        }
    }
    // reduce over the 16 column lanes: VALU-pipe DPP rotate-reduce
    #pragma unroll
    for (int p = 0; p < 4; ++p)
        #pragma unroll
        for (int q = 0; q < 8; ++q)
            acc[p][q] = row16_sum(acc[p][q]);

    if (c16 == 0) {
        #pragma unroll
        for (int p = 0; p < 4; ++p) {
            const int srow = wave * 16 + p * 4 + s4;
            #pragma unroll
            for (int q = 0; q < 8; ++q) hb[srow][q] = acc[p][q];
        }
    }
    __syncthreads();

    // ---------------- circuit phase: transfer-matrix, one sample per thread ----
    // Active: lanes 0..15 of each wave -> 64 samples per block, one per thread.
    if (lane < 16) {
        const int sl   = wave * 16 + lane;     // local sample 0..63
        const int samp = b0 + sl;
        const float scl = scalep[0];

        // per-sample single-qubit input amplitudes: f0=cos(phi/2), f1=sin(phi/2)
        // phi folds the data RY and the layer-0 weight RY (both pre-entangler).
        float f0[8], f1[8];
        #pragma unroll
        for (int q = 0; q < 8; ++q) {
            float ang = fast_tanh(hb[sl][q]) * scl + wts[q];
            __sincosf(0.5f * ang, &f1[q], &f0[q]);
        }
        // layer-1 RY params (uniform): G-tables c^2, s^2, c*s
        float c2[8], s2[8], cs[8];
        #pragma unroll
        for (int q = 0; q < 8; ++q) {
            float sw, cw;
            __sincosf(0.5f * wts[8 + q], &sw, &cw);
            c2[q] = cw * cw; s2[q] = sw * sw; cs[q] = cw * sw;
        }

        // state vector over (b, sym(beta,beta~)): [2][3], t: 0=(00),1=(01/10),2=(11)
        // prefix sweep: Lp[q] = L^(q); Lp[0] = e_{b=0,t=0}
        float Lp[9][2][3];
        Lp[0][0][0] = 1.f; Lp[0][0][1] = 0.f; Lp[0][0][2] = 0.f;
        Lp[0][1][0] = 0.f; Lp[0][1][1] = 0.f; Lp[0][1][2] = 0.f;

        #pragma unroll
        for (int q = 0; q < 8; ++q) {
            const float A = f0[q] * f0[q];
            const float B = f0[q] * f1[q];
            const float C = f1[q] * f1[q];
            float u[2][3];
            #pragma unroll
            for (int b = 0; b < 2; ++b) {
                const float v0 = Lp[q][b][0], v1 = Lp[q][b][1], v2 = Lp[q][b][2];
                u[b][0] = A * v0 + 2.f * B * v1 + C * v2;
                u[b][1] = B * v0 + (A + C) * v1 + B * v2;
                u[b][2] = C * v0 + 2.f * B * v1 + A * v2;
            }
            Lp[q+1][0][0] = c2[q] * u[0][0] + s2[q] * u[1][0];
            Lp[q+1][1][0] = s2[q] * u[0][0] + c2[q] * u[1][0];
            const float m = cs[q] * (u[1][1] - u[0][1]);
            Lp[q+1][0][1] = m;
            Lp[q+1][1][1] = -m;
            Lp[q+1][0][2] = s2[q] * u[0][2] + c2[q] * u[1][2];
            Lp[q+1][1][2] = c2[q] * u[0][2] + s2[q] * u[1][2];
        }

        // suffix sweep + signed dots: z_i = <S^(i+1), (+/- on b) L^(i+1)>
        float S[2][3] = {{1.f, 1.f, 1.f}, {1.f, 1.f, 1.f}};
        float z[8];
        #pragma unroll
        for (int i = 7; i >= 0; --i) {
            z[i] = (S[0][0] * Lp[i+1][0][0] + 2.f * S[0][1] * Lp[i+1][0][1] + S[0][2] * Lp[i+1][0][2])
                 - (S[1][0] * Lp[i+1][1][0] + 2.f * S[1][1] * Lp[i+1][1][1] + S[1][2] * Lp[i+1][1][2]);
            if (i > 0) {
                float u[2][3];
                u[0][0] = c2[i] * S[0][0] + s2[i] * S[1][0];
                u[1][0] = s2[i] * S[0][0] + c2[i] * S[1][0];
                const float m = cs[i] * (S[1][1] - S[0][1]);
                u[0][1] = m; u[1][1] = -m;
                u[0][2] = s2[i] * S[0][2] + c2[i] * S[1][2];
                u[1][2] = c2[i] * S[0][2] + s2[i] * S[1][2];
                const float A = f0[i] * f0[i];
                const float B = f0[i] * f1[i];
                const float C = f1[i] * f1[i];
                #pragma unroll
                for (int b = 0; b < 2; ++b) {
                    const float u0 = u[b][0], u1 = u[b][1], u2 = u[b][2];
                    S[b][0] = A * u0 + 2.f * B * u1 + C * u2;
                    S[b][1] = B * u0 + (A + C) * u1 + B * u2;
                    S[b][2] = C * u0 + 2.f * B * u1 + A * u2;
                }
            }
        }

        float4* o = reinterpret_cast<float4*>(out + (size_t)samp * 8);
        o[0] = make_float4(z[0], z[1], z[2], z[3]);
        o[1] = make_float4(z[4], z[5], z[6], z[7]);
    }
}

extern "C" void kernel_launch(void* const* d_in, const int* in_sizes, int n_in,
                              void* d_out, int out_size, void* d_ws, size_t ws_size,
                              hipStream_t stream) {
    const float* x   = (const float*)d_in[0];
    const float* W   = (const float*)d_in[1];
    const float* sc  = (const float*)d_in[2];
    const float* wt  = (const float*)d_in[3];
    float* o         = (float*)d_out;

    const int batch  = in_sizes[0] / 768;     // 65536
    const int blocks = batch / 64;            // 64 samples per block
    pqc_kernel<<<dim3(blocks), dim3(256), 0, stream>>>(x, W, sc, wt, o);
}